// Round 5
// baseline (659.137 us; speedup 1.0000x reference)
//
#include <hip/hip_runtime.h>
#include <hip/hip_fp16.h>
#include <hip/hip_cooperative_groups.h>

namespace cg = cooperative_groups;

// coif4 decomposition low-pass filter (24 taps). REC_LO[k]=DEC_LO[23-k], REC_HI[k]=(-1)^k*DEC_LO[k]
__device__ __constant__ float DEC_LO[24] = {
    -1.7849850030882614e-06f, -3.2596802368833675e-06f, 3.1229875865345646e-05f,
    6.233903446100713e-05f, -0.00025997455248771324f, -0.0005890207562443383f,
    0.0012665619292989445f, 0.003751436157278457f, -0.00565828668661072f,
    -0.015211731527946259f, 0.025082261844864097f, 0.03933442712333749f,
    -0.09622044203398798f, -0.06662747426342504f, 0.4343860564914685f,
    0.782238930920499f, 0.41530840703043026f, -0.05607731331675481f,
    -0.08126669968087875f, 0.026682300156053072f, 0.016068943964776348f,
    -0.0073461663276420935f, -0.0016294920126017326f, 0.0008923136685823146f
};

struct FusedP {
    const float* yl[6];
    const float* yhb[6];   // [C][3][64][w4]
    const float* yha[6];   // [C][3][128][w2]
    float* x1[6];          // [C][128][w2] fp32
    __half* lo2[6];        // [C][256][w2] fp16
    __half* hi2[6];
    __half* planeH[6];     // [256][W][32] fp16 channel-last
    const float* pts;
    const float* ts;
    int* keys;
    int* hist;
    int* cursor;
    float4* sortedP4;
    int* sortedIdx;
    float* out;
    int Npts;
};

union SMem {
    struct { float lo[32 * 64], hi[32 * 64]; } l1;        // 16 KB
    struct { __half lo[32 * 130], hi[32 * 130]; } ht;     // 16.25 KB (fp16, stride w2+2)
    int scan[256];
};

union H8 {
    float4 f4;
    __half h[8];
};

__device__ __forceinline__ void compute_p4(const float* pts, const float* ts, int p, float* p4) {
    const float sc = (float)(2.0 / (-2.0 * 1.3));
    p4[0] = (pts[p * 3 + 0] - 1.3f) * sc - 1.0f;
    p4[1] = (pts[p * 3 + 1] - 1.3f) * sc - 1.0f;
    p4[2] = (pts[p * 3 + 2] - 1.3f) * sc - 1.0f;
    p4[3] = ts[p] * 2.0f - 1.0f;
}

__device__ __forceinline__ int morton_key(const float* p4) {
    int key = 0;
#pragma unroll
    for (int d = 0; d < 4; ++d) {
        float u = (p4[d] + 1.0f) * 0.5f * 8.0f;
        int ci = (int)u;
        ci = ci < 0 ? 0 : (ci > 7 ? 7 : ci);
#pragma unroll
        for (int b = 0; b < 3; ++b) key |= ((ci >> b) & 1) << (b * 4 + d);
    }
    return key;
}

__global__ __launch_bounds__(256, 4) void fused_k(FusedP a) {
    __shared__ SMem sm;
    cg::grid_group grid = cg::this_grid();
    const int bid = blockIdx.x;
    const int tid = threadIdx.x;
    const int NB = gridDim.x;
    const int GT = NB * 256;

    // ================= Phase 0: idwt level-1 (fused v+h, grid-stride) + zero hist =============
    for (int u = bid; u < 768; u += NB) {
        int rg = u & 3, c = (u >> 2) & 31, i = u >> 7;
        int w4 = (i == 0 || i == 1 || i == 3) ? 64 : 16;
        int lw4 = (w4 == 64) ? 6 : 4;

        const float* llc = a.yl[i] + (size_t)c * 64 * w4;
        const float* lhc = a.yhb[i] + (size_t)(c * 3 + 0) * 64 * w4;
        const float* hlc = a.yhb[i] + (size_t)(c * 3 + 1) * 64 * w4;
        const float* hhc = a.yhb[i] + (size_t)(c * 3 + 2) * 64 * w4;

        // vertical: pairs m in [rg*16, rg*16+16) -> LDS rows [0,32)
        for (int idx = tid; idx < (16 << lw4); idx += 256) {
            int mp = idx >> lw4, x = idx & (w4 - 1);
            int m = rg * 16 + mp;
            float lo0 = 0.f, lo1 = 0.f, hi0 = 0.f, hi1 = 0.f;
#pragma unroll
            for (int j = 0; j < 12; ++j) {
                int r = (m - j) & 63;
                int ii = (r << lw4) + x;
                float vll = llc[ii], vlh = lhc[ii], vhl = hlc[ii], vhh = hhc[ii];
                float rl0 = DEC_LO[23 - 2 * j], rl1 = DEC_LO[22 - 2 * j];
                float rh0 = DEC_LO[2 * j],      rh1 = -DEC_LO[2 * j + 1];
                lo0 += rl0 * vll + rh0 * vlh;
                lo1 += rl1 * vll + rh1 * vlh;
                hi0 += rl0 * vhl + rh0 * vhh;
                hi1 += rl1 * vhl + rh1 * vhh;
            }
            sm.l1.lo[((2 * mp) << lw4) + x] = lo0;
            sm.l1.lo[((2 * mp + 1) << lw4) + x] = lo1;
            sm.l1.hi[((2 * mp) << lw4) + x] = hi0;
            sm.l1.hi[((2 * mp + 1) << lw4) + x] = hi1;
        }
        __syncthreads();

        // horizontal: LDS rows [0,32) -> x1 global rows [rg*32, rg*32+32)
        int w2 = w4 * 2;
        float* x1p = a.x1[i] + (size_t)c * 128 * w2;
        for (int idx = tid; idx < (32 << lw4); idx += 256) {
            int yl = idx >> lw4, mcol = idx & (w4 - 1);
            float o0 = 0.f, o1 = 0.f;
#pragma unroll
            for (int j = 0; j < 12; ++j) {
                int r = (mcol - j) & (w4 - 1);
                float vl = sm.l1.lo[(yl << lw4) + r], vh = sm.l1.hi[(yl << lw4) + r];
                o0 += DEC_LO[23 - 2 * j] * vl + DEC_LO[2 * j] * vh;
                o1 += DEC_LO[22 - 2 * j] * vl - DEC_LO[2 * j + 1] * vh;
            }
            *(float2*)(x1p + (size_t)(rg * 32 + yl) * w2 + 2 * mcol) = make_float2(o0, o1);
        }
        __syncthreads();   // protect LDS reuse on next grid-stride iteration
    }
    for (int i = bid * 256 + tid; i < 4096; i += GT) a.hist[i] = 0;
    grid.sync();

    // ================= Phase 1: idwt level-2 vertical + Morton histogram =================
    {
        const int boff[7] = {0, 2048, 4096, 4608, 6656, 7168, 7680};
        for (int u = bid; u < 7680; u += NB) {
            int i = 0;
            while (i < 5 && u >= boff[i + 1]) ++i;
            int lw2 = (i == 0 || i == 1 || i == 3) ? 7 : 5;
            int w2 = 1 << lw2;
            unsigned t = (unsigned)(u - boff[i]) * 256u + tid;
            unsigned hw = 128u << lw2;
            unsigned c = t >> (7 + lw2);
            unsigned rem = t & (hw - 1);
            unsigned m = rem >> lw2;
            unsigned x = rem & (unsigned)(w2 - 1);

            const float* llc = a.x1[i] + (size_t)c * hw;
            const float* lhc = a.yha[i] + (size_t)(c * 3 + 0) * hw;
            const float* hlc = a.yha[i] + (size_t)(c * 3 + 1) * hw;
            const float* hhc = a.yha[i] + (size_t)(c * 3 + 2) * hw;

            float lo0 = 0.f, lo1 = 0.f, hi0 = 0.f, hi1 = 0.f;
#pragma unroll
            for (int j = 0; j < 12; ++j) {
                int r = ((int)m - j) & 127;
                unsigned idx = ((unsigned)r << lw2) + x;
                float vll = llc[idx], vlh = lhc[idx], vhl = hlc[idx], vhh = hhc[idx];
                float rl0 = DEC_LO[23 - 2 * j], rl1 = DEC_LO[22 - 2 * j];
                float rh0 = DEC_LO[2 * j],      rh1 = -DEC_LO[2 * j + 1];
                lo0 += rl0 * vll + rh0 * vlh;
                lo1 += rl1 * vll + rh1 * vlh;
                hi0 += rl0 * vhl + rh0 * vhh;
                hi1 += rl1 * vhl + rh1 * vhh;
            }
            size_t ob = ((size_t)c * 256 + 2 * m) * w2 + x;
            a.lo2[i][ob] = __float2half(lo0);
            a.lo2[i][ob + w2] = __float2half(lo1);
            a.hi2[i][ob] = __float2half(hi0);
            a.hi2[i][ob + w2] = __float2half(hi1);
        }
        for (int p = bid * 256 + tid; p < a.Npts; p += GT) {
            float p4[4];
            compute_p4(a.pts, a.ts, p, p4);
            int key = morton_key(p4);
            a.keys[p] = key;
            atomicAdd(&a.hist[key], 1);
        }
    }
    grid.sync();

    // ================= Phase 2: scan (block 0) + idwt level-2 horizontal+transpose ==========
    if (bid == 0) {
        int base = tid * 16;
        int loc[16];
        int s = 0;
#pragma unroll
        for (int k = 0; k < 16; ++k) { loc[k] = a.hist[base + k]; s += loc[k]; }
        sm.scan[tid] = s;
        __syncthreads();
        for (int off2 = 1; off2 < 256; off2 <<= 1) {
            int t = (tid >= off2) ? sm.scan[tid - off2] : 0;
            __syncthreads();
            sm.scan[tid] += t;
            __syncthreads();
        }
        int run = (tid > 0) ? sm.scan[tid - 1] : 0;
#pragma unroll
        for (int k = 0; k < 16; ++k) { a.cursor[base + k] = run; run += loc[k]; }
    } else {
        for (int r = bid - 1; r < 1536; r += NB - 1) {
            int i = r >> 8, y = r & 255;
            int lw2 = (i == 0 || i == 1 || i == 3) ? 7 : 5;
            int w2 = 1 << lw2;
            int stride = w2 + 2;  // fp16 LDS; bank = (c + r/2) mod 32 -> conflict-free per c

            for (int idx = tid; idx < (32 << lw2); idx += 256) {
                int c = idx >> lw2, x = idx & (w2 - 1);
                size_t g = ((size_t)c * 256 + y) * w2 + x;
                sm.ht.lo[c * stride + x] = a.lo2[i][g];
                sm.ht.hi[c * stride + x] = a.hi2[i][g];
            }
            __syncthreads();

            int W = 2 * w2;
            __half* orow = a.planeH[i] + (size_t)y * W * 32;
            for (int idx = tid; idx < (32 << lw2); idx += 256) {
                int m = idx >> 5, c = idx & 31;
                float o0 = 0.f, o1 = 0.f;
#pragma unroll
                for (int j = 0; j < 12; ++j) {
                    int r2 = m - j; if (r2 < 0) r2 += w2;
                    float vl = __half2float(sm.ht.lo[c * stride + r2]);
                    float vh = __half2float(sm.ht.hi[c * stride + r2]);
                    o0 += DEC_LO[23 - 2 * j] * vl + DEC_LO[2 * j] * vh;
                    o1 += DEC_LO[22 - 2 * j] * vl - DEC_LO[2 * j + 1] * vh;
                }
                orow[(2 * m) * 32 + c] = __float2half(o0);
                orow[(2 * m + 1) * 32 + c] = __float2half(o1);
            }
            __syncthreads();
        }
    }
    grid.sync();

    // ================= Phase 3: scatter into sorted order =================
    for (int p = bid * 256 + tid; p < a.Npts; p += GT) {
        int key = a.keys[p];
        int pos = atomicAdd(&a.cursor[key], 1);
        float p4[4];
        compute_p4(a.pts, a.ts, p, p4);
        a.sortedP4[pos] = make_float4(p4[0], p4[1], p4[2], p4[3]);
        a.sortedIdx[pos] = p;
    }
    grid.sync();

    // ================= Phase 4: binned bilinear sampling =================
    {
        const int PW[6] = {256, 256, 64, 256, 64, 64};
        const int QI[6] = {0, 0, 3, 1, 3, 3};
        const int RI[6] = {1, 2, 0, 2, 1, 2};
        int total = a.Npts * 4;
        int chunk = (total + NB - 1) / NB;
        int nb8 = NB >> 3;
        int lb = (bid & 7) * nb8 + (bid >> 3);  // XCD-contiguity swizzle (NB multiple of 8)
        int start = lb * chunk;
        int end = start + chunk < total ? start + chunk : total;
        for (int l = start + tid; l < end; l += 256) {
            int p = l >> 2;
            int ch8 = (l & 3) << 3;
            float4 q = a.sortedP4[p];
            int oidx = a.sortedIdx[p];
            float p4[4] = {q.x, q.y, q.z, q.w};

            float acc[8] = {1.f, 1.f, 1.f, 1.f, 1.f, 1.f, 1.f, 1.f};
#pragma unroll
            for (int i = 0; i < 6; ++i) {
                int W = PW[i];
                float cx = p4[QI[i]];
                float cy = p4[RI[i]];
                float fx = (cx + 1.0f) * 0.5f * (float)(W - 1);
                fx = fminf(fmaxf(fx, 0.0f), (float)(W - 1));
                float fy = (cy + 1.0f) * 0.5f * 255.0f;
                fy = fminf(fmaxf(fy, 0.0f), 255.0f);
                float x0 = fminf(fmaxf(floorf(fx), 0.0f), (float)(W - 2));
                float y0 = fminf(fmaxf(floorf(fy), 0.0f), 254.0f);
                float wx = fx - x0, wy = fy - y0;
                int xi = (int)x0, yi = (int)y0;

                const __half* base = a.planeH[i] + ((size_t)yi * W + xi) * 32 + ch8;
                H8 u00, u01, u10, u11;
                u00.f4 = *(const float4*)(base);
                u01.f4 = *(const float4*)(base + 32);
                u10.f4 = *(const float4*)(base + (size_t)W * 32);
                u11.f4 = *(const float4*)(base + (size_t)W * 32 + 32);

                float w00 = (1.f - wy) * (1.f - wx), w01 = (1.f - wy) * wx;
                float w10 = wy * (1.f - wx), w11 = wy * wx;
#pragma unroll
                for (int k = 0; k < 8; ++k) {
                    float f = w00 * __half2float(u00.h[k]) + w01 * __half2float(u01.h[k]) +
                              w10 * __half2float(u10.h[k]) + w11 * __half2float(u11.h[k]);
                    acc[k] *= f;
                }
            }
            float* op = a.out + (size_t)oidx * 32 + ch8;
            *(float4*)(op) = make_float4(acc[0], acc[1], acc[2], acc[3]);
            *(float4*)(op + 4) = make_float4(acc[4], acc[5], acc[6], acc[7]);
        }
    }
}

extern "C" void kernel_launch(void* const* d_in, const int* in_sizes, int n_in,
                              void* d_out, int out_size, void* d_ws, size_t ws_size,
                              hipStream_t stream) {
    const int PWt[6] = {256, 256, 64, 256, 64, 64};
    const int Npts = in_sizes[0] / 3;

    char* ws = (char*)d_ws;
    FusedP a;
    size_t off = 0;
    for (int i = 0; i < 6; ++i) {
        int W = PWt[i], w2 = W / 2;
        a.x1[i] = (float*)(ws + off);      off += (size_t)32 * 128 * w2 * 4;
        a.lo2[i] = (__half*)(ws + off);    off += (size_t)32 * 256 * w2 * 2;
        a.hi2[i] = (__half*)(ws + off);    off += (size_t)32 * 256 * w2 * 2;
        a.planeH[i] = (__half*)(ws + off); off += (size_t)256 * W * 32 * 2;
    }
    off = (off + 15) & ~(size_t)15;
    a.sortedP4 = (float4*)(ws + off); off += (size_t)Npts * 16;
    a.keys = (int*)(ws + off);        off += (size_t)Npts * 4;
    a.sortedIdx = (int*)(ws + off);   off += (size_t)Npts * 4;
    a.hist = (int*)(ws + off);        off += 4096 * 4;
    a.cursor = (int*)(ws + off);      off += 4096 * 4;

    a.pts = (const float*)d_in[0];
    a.ts = (const float*)d_in[1];
    for (int i = 0; i < 6; ++i) {
        a.yl[i] = (const float*)d_in[2 + 3 * i];
        a.yha[i] = (const float*)d_in[3 + 3 * i];
        a.yhb[i] = (const float*)d_in[4 + 3 * i];
    }
    a.out = (float*)d_out;
    a.Npts = Npts;

    // Size the grid to guaranteed co-residency (host-only queries; deterministic; capture-safe).
    int dev = 0;
    hipGetDevice(&dev);
    int cus = 0;
    if (hipDeviceGetAttribute(&cus, hipDeviceAttributeMultiprocessorCount, dev) != hipSuccess || cus <= 0)
        cus = 256;
    int perCU = 0;
    if (hipOccupancyMaxActiveBlocksPerMultiprocessor(&perCU, fused_k, 256, 0) != hipSuccess || perCU < 1)
        perCU = 1;
    int grid = perCU * cus;
    if (grid > 1024) grid = 1024;
    grid &= ~7;             // multiple of 8 for the XCD swizzle
    if (grid < 8) grid = 8;

    void* kargs[] = {(void*)&a};
    hipLaunchCooperativeKernel((const void*)fused_k, dim3(grid), dim3(256), kargs, 0, stream);
}

// Round 6
// 491.492 us; speedup vs baseline: 1.3411x; 1.3411x over previous
//
#include <hip/hip_runtime.h>
#include <hip/hip_fp16.h>

#define NSLICE 64
#define NBIN 4096

// coif4 decomposition low-pass filter (24 taps). REC_LO[k]=DEC_LO[23-k], REC_HI[k]=(-1)^k*DEC_LO[k]
__device__ __constant__ float DEC_LO[24] = {
    -1.7849850030882614e-06f, -3.2596802368833675e-06f, 3.1229875865345646e-05f,
    6.233903446100713e-05f, -0.00025997455248771324f, -0.0005890207562443383f,
    0.0012665619292989445f, 0.003751436157278457f, -0.00565828668661072f,
    -0.015211731527946259f, 0.025082261844864097f, 0.03933442712333749f,
    -0.09622044203398798f, -0.06662747426342504f, 0.4343860564914685f,
    0.782238930920499f, 0.41530840703043026f, -0.05607731331675481f,
    -0.08126669968087875f, 0.026682300156053072f, 0.016068943964776348f,
    -0.0073461663276420935f, -0.0016294920126017326f, 0.0008923136685823146f
};

struct PK {
    const float* yl[6];
    const float* yhb[6];   // [C][3][64][w4]
    const float* yha[6];   // [C][3][128][w2]
    float* x1[6];          // [C][128][w2] fp32
    __half* lo2[6];        // [C][256][w2] fp16
    __half* hi2[6];
    __half* planeH[6];     // [256][W][32] fp16 channel-last
    const float* pts;
    const float* ts;
    int* keys;
    int* histS;            // [NSLICE][NBIN]
    int* curS;             // [NSLICE][NBIN]
    float4* sortedP4;
    int* sortedIdx;
    int Npts, chunk;
};

__device__ __forceinline__ void compute_p4(const float* pts, const float* ts, int p, float* p4) {
    const float sc = (float)(2.0 / (-2.0 * 1.3));
    p4[0] = (pts[p * 3 + 0] - 1.3f) * sc - 1.0f;
    p4[1] = (pts[p * 3 + 1] - 1.3f) * sc - 1.0f;
    p4[2] = (pts[p * 3 + 2] - 1.3f) * sc - 1.0f;
    p4[3] = ts[p] * 2.0f - 1.0f;
}

__device__ __forceinline__ int morton_key(const float* p4) {
    int key = 0;
#pragma unroll
    for (int d = 0; d < 4; ++d) {
        float u = (p4[d] + 1.0f) * 0.5f * 8.0f;
        int ci = (int)u;
        ci = ci < 0 ? 0 : (ci > 7 ? 7 : ci);
#pragma unroll
        for (int b = 0; b < 3; ++b) key |= ((ci >> b) & 1) << (b * 4 + d);
    }
    return key;
}

// ============ K1: idwt level-1 (blocks 0..767) || per-slice histogram (blocks 768..831) ========
__global__ __launch_bounds__(256) void k1_l1_hist(PK a) {
    __shared__ union { struct { float lo[32 * 64], hi[32 * 64]; } l1; int hist[NBIN]; } sm;
    int bid = blockIdx.x, tid = threadIdx.x;

    if (bid < 768) {
        int rg = bid & 3, c = (bid >> 2) & 31, i = bid >> 7;
        int w4 = (i == 0 || i == 1 || i == 3) ? 64 : 16;
        int lw4 = (w4 == 64) ? 6 : 4;

        const float* llc = a.yl[i] + (size_t)c * 64 * w4;
        const float* lhc = a.yhb[i] + (size_t)(c * 3 + 0) * 64 * w4;
        const float* hlc = a.yhb[i] + (size_t)(c * 3 + 1) * 64 * w4;
        const float* hhc = a.yhb[i] + (size_t)(c * 3 + 2) * 64 * w4;

        for (int idx = tid; idx < (16 << lw4); idx += 256) {
            int mp = idx >> lw4, x = idx & (w4 - 1);
            int m = rg * 16 + mp;
            float lo0 = 0.f, lo1 = 0.f, hi0 = 0.f, hi1 = 0.f;
#pragma unroll
            for (int j = 0; j < 12; ++j) {
                int r = (m - j) & 63;
                int ii = (r << lw4) + x;
                float vll = llc[ii], vlh = lhc[ii], vhl = hlc[ii], vhh = hhc[ii];
                float rl0 = DEC_LO[23 - 2 * j], rl1 = DEC_LO[22 - 2 * j];
                float rh0 = DEC_LO[2 * j],      rh1 = -DEC_LO[2 * j + 1];
                lo0 += rl0 * vll + rh0 * vlh;
                lo1 += rl1 * vll + rh1 * vlh;
                hi0 += rl0 * vhl + rh0 * vhh;
                hi1 += rl1 * vhl + rh1 * vhh;
            }
            sm.l1.lo[((2 * mp) << lw4) + x] = lo0;
            sm.l1.lo[((2 * mp + 1) << lw4) + x] = lo1;
            sm.l1.hi[((2 * mp) << lw4) + x] = hi0;
            sm.l1.hi[((2 * mp + 1) << lw4) + x] = hi1;
        }
        __syncthreads();

        int w2 = w4 * 2;
        float* x1p = a.x1[i] + (size_t)c * 128 * w2;
        for (int idx = tid; idx < (32 << lw4); idx += 256) {
            int yl = idx >> lw4, mcol = idx & (w4 - 1);
            float o0 = 0.f, o1 = 0.f;
#pragma unroll
            for (int j = 0; j < 12; ++j) {
                int r = (mcol - j) & (w4 - 1);
                float vl = sm.l1.lo[(yl << lw4) + r], vh = sm.l1.hi[(yl << lw4) + r];
                o0 += DEC_LO[23 - 2 * j] * vl + DEC_LO[2 * j] * vh;
                o1 += DEC_LO[22 - 2 * j] * vl - DEC_LO[2 * j + 1] * vh;
            }
            *(float2*)(x1p + (size_t)(rg * 32 + yl) * w2 + 2 * mcol) = make_float2(o0, o1);
        }
    } else {
        int b = bid - 768;
        for (int k = tid; k < NBIN; k += 256) sm.hist[k] = 0;
        __syncthreads();
        int start = b * a.chunk;
        int end = start + a.chunk < a.Npts ? start + a.chunk : a.Npts;
        for (int p = start + tid; p < end; p += 256) {
            float p4[4];
            compute_p4(a.pts, a.ts, p, p4);
            int key = morton_key(p4);
            a.keys[p] = key;
            atomicAdd(&sm.hist[key], 1);
        }
        __syncthreads();
        int* dst = a.histS + b * NBIN;
        for (int k = tid; k < NBIN; k += 256) dst[k] = sm.hist[k];
    }
}

// ============ K2: idwt level-2 vertical (blocks 0..7679) || scan (block 7680) ==================
__global__ __launch_bounds__(256) void k2_v2_scan(PK a) {
    __shared__ int s_scan[256];
    int bid = blockIdx.x, tid = threadIdx.x;

    if (bid < 7680) {
        const int boff[7] = {0, 2048, 4096, 4608, 6656, 7168, 7680};
        int i = 0;
        while (i < 5 && bid >= boff[i + 1]) ++i;
        int lw2 = (i == 0 || i == 1 || i == 3) ? 7 : 5;
        int w2 = 1 << lw2;
        unsigned t = (unsigned)(bid - boff[i]) * 256u + tid;
        unsigned hw = 128u << lw2;
        unsigned c = t >> (7 + lw2);
        unsigned rem = t & (hw - 1);
        unsigned m = rem >> lw2;
        unsigned x = rem & (unsigned)(w2 - 1);

        const float* llc = a.x1[i] + (size_t)c * hw;
        const float* lhc = a.yha[i] + (size_t)(c * 3 + 0) * hw;
        const float* hlc = a.yha[i] + (size_t)(c * 3 + 1) * hw;
        const float* hhc = a.yha[i] + (size_t)(c * 3 + 2) * hw;

        float lo0 = 0.f, lo1 = 0.f, hi0 = 0.f, hi1 = 0.f;
#pragma unroll
        for (int j = 0; j < 12; ++j) {
            int r = ((int)m - j) & 127;
            unsigned idx = ((unsigned)r << lw2) + x;
            float vll = llc[idx], vlh = lhc[idx], vhl = hlc[idx], vhh = hhc[idx];
            float rl0 = DEC_LO[23 - 2 * j], rl1 = DEC_LO[22 - 2 * j];
            float rh0 = DEC_LO[2 * j],      rh1 = -DEC_LO[2 * j + 1];
            lo0 += rl0 * vll + rh0 * vlh;
            lo1 += rl1 * vll + rh1 * vlh;
            hi0 += rl0 * vhl + rh0 * vhh;
            hi1 += rl1 * vhl + rh1 * vhh;
        }
        size_t ob = ((size_t)c * 256 + 2 * m) * w2 + x;
        a.lo2[i][ob] = __float2half(lo0);
        a.lo2[i][ob + w2] = __float2half(lo1);
        a.hi2[i][ob] = __float2half(hi0);
        a.hi2[i][ob + w2] = __float2half(hi1);
    } else {
        // scan: thread t owns bins [t*16, t*16+16)
        int base = tid * 16;
        int totals[16];
#pragma unroll
        for (int k = 0; k < 16; ++k) totals[k] = 0;
        for (int b = 0; b < NSLICE; ++b) {
            const int* hp = a.histS + b * NBIN + base;
#pragma unroll
            for (int k = 0; k < 16; ++k) totals[k] += hp[k];
        }
        int tsum = 0;
#pragma unroll
        for (int k = 0; k < 16; ++k) tsum += totals[k];
        s_scan[tid] = tsum;
        __syncthreads();
        for (int off = 1; off < 256; off <<= 1) {
            int v = (tid >= off) ? s_scan[tid - off] : 0;
            __syncthreads();
            s_scan[tid] += v;
            __syncthreads();
        }
        int run[16];
        int r0 = (tid > 0) ? s_scan[tid - 1] : 0;
#pragma unroll
        for (int k = 0; k < 16; ++k) { run[k] = r0; r0 += totals[k]; }
        for (int b = 0; b < NSLICE; ++b) {
            const int* hp = a.histS + b * NBIN + base;
            int* cp = a.curS + b * NBIN + base;
#pragma unroll
            for (int k = 0; k < 16; ++k) { int h = hp[k]; cp[k] = run[k]; run[k] += h; }
        }
    }
}

// ============ K3: idwt l2 horizontal+transpose (blocks 0..1535) || scatter (1536..1599) ========
__global__ __launch_bounds__(256) void k3_ht_scatter(PK a) {
    __shared__ union { struct { __half lo[32 * 130], hi[32 * 130]; } ht; int cur[NBIN]; } sm;
    int bid = blockIdx.x, tid = threadIdx.x;

    if (bid < 1536) {
        int i = bid >> 8, y = bid & 255;
        int lw2 = (i == 0 || i == 1 || i == 3) ? 7 : 5;
        int w2 = 1 << lw2;
        int stride = w2 + 2;  // fp16 LDS: bank (c + r/2) mod 32 -> conflict-free column reads

        for (int idx = tid; idx < (32 << lw2); idx += 256) {
            int c = idx >> lw2, x = idx & (w2 - 1);
            size_t g = ((size_t)c * 256 + y) * w2 + x;
            sm.ht.lo[c * stride + x] = a.lo2[i][g];
            sm.ht.hi[c * stride + x] = a.hi2[i][g];
        }
        __syncthreads();

        int W = 2 * w2;
        __half* orow = a.planeH[i] + (size_t)y * W * 32;
        for (int idx = tid; idx < (32 << lw2); idx += 256) {
            int m = idx >> 5, c = idx & 31;
            float o0 = 0.f, o1 = 0.f;
#pragma unroll
            for (int j = 0; j < 12; ++j) {
                int r2 = m - j; if (r2 < 0) r2 += w2;
                float vl = __half2float(sm.ht.lo[c * stride + r2]);
                float vh = __half2float(sm.ht.hi[c * stride + r2]);
                o0 += DEC_LO[23 - 2 * j] * vl + DEC_LO[2 * j] * vh;
                o1 += DEC_LO[22 - 2 * j] * vl - DEC_LO[2 * j + 1] * vh;
            }
            orow[(2 * m) * 32 + c] = __float2half(o0);
            orow[(2 * m + 1) * 32 + c] = __float2half(o1);
        }
    } else {
        int b = bid - 1536;
        const int* cp = a.curS + b * NBIN;
        for (int k = tid; k < NBIN; k += 256) sm.cur[k] = cp[k];
        __syncthreads();
        int start = b * a.chunk;
        int end = start + a.chunk < a.Npts ? start + a.chunk : a.Npts;
        for (int p = start + tid; p < end; p += 256) {
            int key = a.keys[p];
            int pos = atomicAdd(&sm.cur[key], 1);
            float p4[4];
            compute_p4(a.pts, a.ts, p, p4);
            a.sortedP4[pos] = make_float4(p4[0], p4[1], p4[2], p4[3]);
            a.sortedIdx[pos] = p;
        }
    }
}

// ============ K4: binned bilinear sampling (4 lanes/point, 8 channels/lane) ====================
struct S6h { const __half* pl[6]; };
union H8 { float4 f4; __half h[8]; };

__global__ __launch_bounds__(256) void sample_k(const float4* __restrict__ sortedP4,
                                                const int* __restrict__ sortedIdx,
                                                S6h a, float* __restrict__ out, int Npts) {
    int nb8 = gridDim.x >> 3;
    int lb = (blockIdx.x & 7) * nb8 + (blockIdx.x >> 3);  // XCD-contiguity swizzle
    int g = lb * 256 + threadIdx.x;
    int p = g >> 2;
    int ch8 = (g & 3) << 3;
    if (p >= Npts) return;

    float4 q = sortedP4[p];
    int oidx = sortedIdx[p];
    float p4[4] = {q.x, q.y, q.z, q.w};

    const int PW[6] = {256, 256, 64, 256, 64, 64};
    const int QI[6] = {0, 0, 3, 1, 3, 3};
    const int RI[6] = {1, 2, 0, 2, 1, 2};

    float acc[8] = {1.f, 1.f, 1.f, 1.f, 1.f, 1.f, 1.f, 1.f};
#pragma unroll
    for (int i = 0; i < 6; ++i) {
        int W = PW[i];
        float cx = p4[QI[i]];
        float cy = p4[RI[i]];
        float fx = (cx + 1.0f) * 0.5f * (float)(W - 1);
        fx = fminf(fmaxf(fx, 0.0f), (float)(W - 1));
        float fy = (cy + 1.0f) * 0.5f * 255.0f;
        fy = fminf(fmaxf(fy, 0.0f), 255.0f);
        float x0 = fminf(fmaxf(floorf(fx), 0.0f), (float)(W - 2));
        float y0 = fminf(fmaxf(floorf(fy), 0.0f), 254.0f);
        float wx = fx - x0, wy = fy - y0;
        int xi = (int)x0, yi = (int)y0;

        const __half* base = a.pl[i] + ((size_t)yi * W + xi) * 32 + ch8;
        H8 u00, u01, u10, u11;
        u00.f4 = *(const float4*)(base);
        u01.f4 = *(const float4*)(base + 32);
        u10.f4 = *(const float4*)(base + (size_t)W * 32);
        u11.f4 = *(const float4*)(base + (size_t)W * 32 + 32);

        float w00 = (1.f - wy) * (1.f - wx), w01 = (1.f - wy) * wx;
        float w10 = wy * (1.f - wx), w11 = wy * wx;
#pragma unroll
        for (int k = 0; k < 8; ++k) {
            float f = w00 * __half2float(u00.h[k]) + w01 * __half2float(u01.h[k]) +
                      w10 * __half2float(u10.h[k]) + w11 * __half2float(u11.h[k]);
            acc[k] *= f;
        }
    }
    float* op = out + (size_t)oidx * 32 + ch8;
    *(float4*)(op) = make_float4(acc[0], acc[1], acc[2], acc[3]);
    *(float4*)(op + 4) = make_float4(acc[4], acc[5], acc[6], acc[7]);
}

extern "C" void kernel_launch(void* const* d_in, const int* in_sizes, int n_in,
                              void* d_out, int out_size, void* d_ws, size_t ws_size,
                              hipStream_t stream) {
    const int PWt[6] = {256, 256, 64, 256, 64, 64};
    const int Npts = in_sizes[0] / 3;

    char* ws = (char*)d_ws;
    PK a;
    size_t off = 0;
    for (int i = 0; i < 6; ++i) {
        int W = PWt[i], w2 = W / 2;
        a.x1[i] = (float*)(ws + off);      off += (size_t)32 * 128 * w2 * 4;
        a.lo2[i] = (__half*)(ws + off);    off += (size_t)32 * 256 * w2 * 2;
        a.hi2[i] = (__half*)(ws + off);    off += (size_t)32 * 256 * w2 * 2;
        a.planeH[i] = (__half*)(ws + off); off += (size_t)256 * W * 32 * 2;
    }
    off = (off + 15) & ~(size_t)15;
    a.sortedP4 = (float4*)(ws + off); off += (size_t)Npts * 16;
    a.keys = (int*)(ws + off);        off += (size_t)Npts * 4;
    a.sortedIdx = (int*)(ws + off);   off += (size_t)Npts * 4;
    a.histS = (int*)(ws + off);       off += (size_t)NSLICE * NBIN * 4;
    a.curS = (int*)(ws + off);        off += (size_t)NSLICE * NBIN * 4;

    a.pts = (const float*)d_in[0];
    a.ts = (const float*)d_in[1];
    for (int i = 0; i < 6; ++i) {
        a.yl[i] = (const float*)d_in[2 + 3 * i];
        a.yha[i] = (const float*)d_in[3 + 3 * i];
        a.yhb[i] = (const float*)d_in[4 + 3 * i];
    }
    a.Npts = Npts;
    a.chunk = (Npts + NSLICE - 1) / NSLICE;

    k1_l1_hist<<<768 + NSLICE, 256, 0, stream>>>(a);
    k2_v2_scan<<<7680 + 1, 256, 0, stream>>>(a);
    k3_ht_scatter<<<1536 + NSLICE, 256, 0, stream>>>(a);

    S6h s;
    for (int i = 0; i < 6; ++i) s.pl[i] = a.planeH[i];
    int total = Npts * 4;
    int blocks = (total + 255) / 256;
    blocks = (blocks + 7) & ~7;  // multiple of 8 for the XCD swizzle
    sample_k<<<blocks, 256, 0, stream>>>(a.sortedP4, a.sortedIdx, s, (float*)d_out, Npts);
}

// Round 7
// 275.206 us; speedup vs baseline: 2.3951x; 1.7859x over previous
//
#include <hip/hip_runtime.h>
#include <hip/hip_fp16.h>

#define NBIN 4096
#define CAP 256
#define OVCAP 65536

// coif4 decomposition low-pass filter (24 taps). REC_LO[k]=DEC_LO[23-k], REC_HI[k]=(-1)^k*DEC_LO[k]
__device__ __constant__ float DEC_LO[24] = {
    -1.7849850030882614e-06f, -3.2596802368833675e-06f, 3.1229875865345646e-05f,
    6.233903446100713e-05f, -0.00025997455248771324f, -0.0005890207562443383f,
    0.0012665619292989445f, 0.003751436157278457f, -0.00565828668661072f,
    -0.015211731527946259f, 0.025082261844864097f, 0.03933442712333749f,
    -0.09622044203398798f, -0.06662747426342504f, 0.4343860564914685f,
    0.782238930920499f, 0.41530840703043026f, -0.05607731331675481f,
    -0.08126669968087875f, 0.026682300156053072f, 0.016068943964776348f,
    -0.0073461663276420935f, -0.0016294920126017326f, 0.0008923136685823146f
};

struct PK {
    const float* yl[6];
    const float* yhb[6];   // [C][3][64][w4]
    const float* yha[6];   // [C][3][128][w2]
    float* x1[6];          // [C][128][w2] fp32
    __half* lo2[6];        // [C][256][w2] fp16
    __half* hi2[6];
    __half* planeH[6];     // [256][W][32] fp16 channel-last
    const float* pts;
    const float* ts;
    int* cnt;              // [NBIN] + ovCnt at cnt[NBIN]
    float4* binP4;         // [NBIN][CAP]
    int* binIdx;           // [NBIN][CAP]
    float4* ovP4;          // [OVCAP]
    int* ovIdx;
    int Npts;
};

__device__ __forceinline__ void compute_p4(const float* pts, const float* ts, int p, float* p4) {
    const float sc = (float)(2.0 / (-2.0 * 1.3));
    p4[0] = (pts[p * 3 + 0] - 1.3f) * sc - 1.0f;
    p4[1] = (pts[p * 3 + 1] - 1.3f) * sc - 1.0f;
    p4[2] = (pts[p * 3 + 2] - 1.3f) * sc - 1.0f;
    p4[3] = ts[p] * 2.0f - 1.0f;
}

__device__ __forceinline__ int morton_key(const float* p4) {
    int key = 0;
#pragma unroll
    for (int d = 0; d < 4; ++d) {
        float u = (p4[d] + 1.0f) * 0.5f * 8.0f;
        int ci = (int)u;
        ci = ci < 0 ? 0 : (ci > 7 ? 7 : ci);
#pragma unroll
        for (int b = 0; b < 3; ++b) key |= ((ci >> b) & 1) << (b * 4 + d);
    }
    return key;
}

// ============ K1: idwt level-1 (blocks 0..767) || zero counters (768..784) ========
__global__ __launch_bounds__(256) void k1_l1_zero(PK a) {
    __shared__ struct { float lo[32 * 64], hi[32 * 64]; } sm;
    int bid = blockIdx.x, tid = threadIdx.x;

    if (bid < 768) {
        int rg = bid & 3, c = (bid >> 2) & 31, i = bid >> 7;
        int w4 = (i == 0 || i == 1 || i == 3) ? 64 : 16;
        int lw4 = (w4 == 64) ? 6 : 4;

        const float* llc = a.yl[i] + (size_t)c * 64 * w4;
        const float* lhc = a.yhb[i] + (size_t)(c * 3 + 0) * 64 * w4;
        const float* hlc = a.yhb[i] + (size_t)(c * 3 + 1) * 64 * w4;
        const float* hhc = a.yhb[i] + (size_t)(c * 3 + 2) * 64 * w4;

        for (int idx = tid; idx < (16 << lw4); idx += 256) {
            int mp = idx >> lw4, x = idx & (w4 - 1);
            int m = rg * 16 + mp;
            float lo0 = 0.f, lo1 = 0.f, hi0 = 0.f, hi1 = 0.f;
#pragma unroll
            for (int j = 0; j < 12; ++j) {
                int r = (m - j) & 63;
                int ii = (r << lw4) + x;
                float vll = llc[ii], vlh = lhc[ii], vhl = hlc[ii], vhh = hhc[ii];
                float rl0 = DEC_LO[23 - 2 * j], rl1 = DEC_LO[22 - 2 * j];
                float rh0 = DEC_LO[2 * j],      rh1 = -DEC_LO[2 * j + 1];
                lo0 += rl0 * vll + rh0 * vlh;
                lo1 += rl1 * vll + rh1 * vlh;
                hi0 += rl0 * vhl + rh0 * vhh;
                hi1 += rl1 * vhl + rh1 * vhh;
            }
            sm.lo[((2 * mp) << lw4) + x] = lo0;
            sm.lo[((2 * mp + 1) << lw4) + x] = lo1;
            sm.hi[((2 * mp) << lw4) + x] = hi0;
            sm.hi[((2 * mp + 1) << lw4) + x] = hi1;
        }
        __syncthreads();

        int w2 = w4 * 2;
        float* x1p = a.x1[i] + (size_t)c * 128 * w2;
        for (int idx = tid; idx < (32 << lw4); idx += 256) {
            int yl = idx >> lw4, mcol = idx & (w4 - 1);
            float o0 = 0.f, o1 = 0.f;
#pragma unroll
            for (int j = 0; j < 12; ++j) {
                int r = (mcol - j) & (w4 - 1);
                float vl = sm.lo[(yl << lw4) + r], vh = sm.hi[(yl << lw4) + r];
                o0 += DEC_LO[23 - 2 * j] * vl + DEC_LO[2 * j] * vh;
                o1 += DEC_LO[22 - 2 * j] * vl - DEC_LO[2 * j + 1] * vh;
            }
            *(float2*)(x1p + (size_t)(rg * 32 + yl) * w2 + 2 * mcol) = make_float2(o0, o1);
        }
    } else {
        int idx = (bid - 768) * 256 + tid;
        if (idx <= NBIN) a.cnt[idx] = 0;   // 4096 bins + ovCnt
    }
}

// ============ K2: idwt level-2 vertical (0..7679) || binned scatter (7680..8191) ==========
__global__ __launch_bounds__(256) void k2_v2_scatter(PK a) {
    int bid = blockIdx.x, tid = threadIdx.x;

    if (bid < 7680) {
        const int boff[7] = {0, 2048, 4096, 4608, 6656, 7168, 7680};
        int i = 0;
        while (i < 5 && bid >= boff[i + 1]) ++i;
        int lw2 = (i == 0 || i == 1 || i == 3) ? 7 : 5;
        int w2 = 1 << lw2;
        unsigned t = (unsigned)(bid - boff[i]) * 256u + tid;
        unsigned hw = 128u << lw2;
        unsigned c = t >> (7 + lw2);
        unsigned rem = t & (hw - 1);
        unsigned m = rem >> lw2;
        unsigned x = rem & (unsigned)(w2 - 1);

        const float* llc = a.x1[i] + (size_t)c * hw;
        const float* lhc = a.yha[i] + (size_t)(c * 3 + 0) * hw;
        const float* hlc = a.yha[i] + (size_t)(c * 3 + 1) * hw;
        const float* hhc = a.yha[i] + (size_t)(c * 3 + 2) * hw;

        float lo0 = 0.f, lo1 = 0.f, hi0 = 0.f, hi1 = 0.f;
#pragma unroll
        for (int j = 0; j < 12; ++j) {
            int r = ((int)m - j) & 127;
            unsigned idx = ((unsigned)r << lw2) + x;
            float vll = llc[idx], vlh = lhc[idx], vhl = hlc[idx], vhh = hhc[idx];
            float rl0 = DEC_LO[23 - 2 * j], rl1 = DEC_LO[22 - 2 * j];
            float rh0 = DEC_LO[2 * j],      rh1 = -DEC_LO[2 * j + 1];
            lo0 += rl0 * vll + rh0 * vlh;
            lo1 += rl1 * vll + rh1 * vlh;
            hi0 += rl0 * vhl + rh0 * vhh;
            hi1 += rl1 * vhl + rh1 * vhh;
        }
        size_t ob = ((size_t)c * 256 + 2 * m) * w2 + x;
        a.lo2[i][ob] = __float2half(lo0);
        a.lo2[i][ob + w2] = __float2half(lo1);
        a.hi2[i][ob] = __float2half(hi0);
        a.hi2[i][ob + w2] = __float2half(hi1);
    } else {
        for (int p = (bid - 7680) * 256 + tid; p < a.Npts; p += 512 * 256) {
            float p4[4];
            compute_p4(a.pts, a.ts, p, p4);
            int key = morton_key(p4);
            int pos = atomicAdd(&a.cnt[key], 1);
            if (pos < CAP) {
                a.binP4[key * CAP + pos] = make_float4(p4[0], p4[1], p4[2], p4[3]);
                a.binIdx[key * CAP + pos] = p;
            } else {
                int ov = atomicAdd(&a.cnt[NBIN], 1);
                if (ov < OVCAP) {
                    a.ovP4[ov] = make_float4(p4[0], p4[1], p4[2], p4[3]);
                    a.ovIdx[ov] = p;
                }
            }
        }
    }
}

// ============ K3: idwt l2 horizontal + transpose (1536 blocks) ========
__global__ __launch_bounds__(256) void k3_ht(PK a) {
    __shared__ struct { __half lo[32 * 130], hi[32 * 130]; } sm;
    int bid = blockIdx.x, tid = threadIdx.x;
    int i = bid >> 8, y = bid & 255;
    int lw2 = (i == 0 || i == 1 || i == 3) ? 7 : 5;
    int w2 = 1 << lw2;
    int stride = w2 + 2;  // fp16 LDS: conflict-free column reads

    for (int idx = tid; idx < (32 << lw2); idx += 256) {
        int c = idx >> lw2, x = idx & (w2 - 1);
        size_t g = ((size_t)c * 256 + y) * w2 + x;
        sm.lo[c * stride + x] = a.lo2[i][g];
        sm.hi[c * stride + x] = a.hi2[i][g];
    }
    __syncthreads();

    int W = 2 * w2;
    __half* orow = a.planeH[i] + (size_t)y * W * 32;
    for (int idx = tid; idx < (32 << lw2); idx += 256) {
        int m = idx >> 5, c = idx & 31;
        float o0 = 0.f, o1 = 0.f;
#pragma unroll
        for (int j = 0; j < 12; ++j) {
            int r2 = m - j; if (r2 < 0) r2 += w2;
            float vl = __half2float(sm.lo[c * stride + r2]);
            float vh = __half2float(sm.hi[c * stride + r2]);
            o0 += DEC_LO[23 - 2 * j] * vl + DEC_LO[2 * j] * vh;
            o1 += DEC_LO[22 - 2 * j] * vl - DEC_LO[2 * j + 1] * vh;
        }
        orow[(2 * m) * 32 + c] = __float2half(o0);
        orow[(2 * m + 1) * 32 + c] = __float2half(o1);
    }
}

// ============ K4: sampling, block-per-bin (+8 overflow blocks) ========
union H8 { float4 f4; __half h[8]; };

struct SK {
    const __half* pl[6];
    const float4* binP4;
    const int* binIdx;
    const int* cnt;
    const float4* ovP4;
    const int* ovIdx;
    float* out;
};

__device__ __forceinline__ void sample_point(const SK& a, const float* p4, int oidx, int ch8) {
    const int PW[6] = {256, 256, 64, 256, 64, 64};
    const int QI[6] = {0, 0, 3, 1, 3, 3};
    const int RI[6] = {1, 2, 0, 2, 1, 2};
    float acc[8] = {1.f, 1.f, 1.f, 1.f, 1.f, 1.f, 1.f, 1.f};
#pragma unroll
    for (int i = 0; i < 6; ++i) {
        int W = PW[i];
        float cx = p4[QI[i]];
        float cy = p4[RI[i]];
        float fx = (cx + 1.0f) * 0.5f * (float)(W - 1);
        fx = fminf(fmaxf(fx, 0.0f), (float)(W - 1));
        float fy = (cy + 1.0f) * 0.5f * 255.0f;
        fy = fminf(fmaxf(fy, 0.0f), 255.0f);
        float x0 = fminf(fmaxf(floorf(fx), 0.0f), (float)(W - 2));
        float y0 = fminf(fmaxf(floorf(fy), 0.0f), 254.0f);
        float wx = fx - x0, wy = fy - y0;
        int xi = (int)x0, yi = (int)y0;

        const __half* base = a.pl[i] + ((size_t)yi * W + xi) * 32 + ch8;
        H8 u00, u01, u10, u11;
        u00.f4 = *(const float4*)(base);
        u01.f4 = *(const float4*)(base + 32);
        u10.f4 = *(const float4*)(base + (size_t)W * 32);
        u11.f4 = *(const float4*)(base + (size_t)W * 32 + 32);

        float w00 = (1.f - wy) * (1.f - wx), w01 = (1.f - wy) * wx;
        float w10 = wy * (1.f - wx), w11 = wy * wx;
#pragma unroll
        for (int k = 0; k < 8; ++k) {
            float f = w00 * __half2float(u00.h[k]) + w01 * __half2float(u01.h[k]) +
                      w10 * __half2float(u10.h[k]) + w11 * __half2float(u11.h[k]);
            acc[k] *= f;
        }
    }
    float* op = a.out + (size_t)oidx * 32 + ch8;
    *(float4*)(op) = make_float4(acc[0], acc[1], acc[2], acc[3]);
    *(float4*)(op + 4) = make_float4(acc[4], acc[5], acc[6], acc[7]);
}

__global__ __launch_bounds__(256) void k4_sample(SK a) {
    int bid = blockIdx.x, tid = threadIdx.x;
    if (bid < NBIN) {
        int bin = (bid & 7) * (NBIN / 8) + (bid >> 3);  // contiguous Morton range per XCD
        int n = a.cnt[bin];
        n = n < CAP ? n : CAP;
        const float4* bp = a.binP4 + bin * CAP;
        const int* bi = a.binIdx + bin * CAP;
        for (int l = tid; l < n * 4; l += 256) {
            int s = l >> 2, ch8 = (l & 3) << 3;
            float4 q = bp[s];
            float p4[4] = {q.x, q.y, q.z, q.w};
            sample_point(a, p4, bi[s], ch8);
        }
    } else {
        int ov = a.cnt[NBIN];
        ov = ov < OVCAP ? ov : OVCAP;
        for (int l = (bid - NBIN) * 256 + tid; l < ov * 4; l += 8 * 256) {
            int s = l >> 2, ch8 = (l & 3) << 3;
            float4 q = a.ovP4[s];
            float p4[4] = {q.x, q.y, q.z, q.w};
            sample_point(a, p4, a.ovIdx[s], ch8);
        }
    }
}

extern "C" void kernel_launch(void* const* d_in, const int* in_sizes, int n_in,
                              void* d_out, int out_size, void* d_ws, size_t ws_size,
                              hipStream_t stream) {
    const int PWt[6] = {256, 256, 64, 256, 64, 64};
    const int Npts = in_sizes[0] / 3;

    char* ws = (char*)d_ws;
    PK a;
    size_t off = 0;
    for (int i = 0; i < 6; ++i) {
        int W = PWt[i], w2 = W / 2;
        a.x1[i] = (float*)(ws + off);      off += (size_t)32 * 128 * w2 * 4;
        a.lo2[i] = (__half*)(ws + off);    off += (size_t)32 * 256 * w2 * 2;
        a.hi2[i] = (__half*)(ws + off);    off += (size_t)32 * 256 * w2 * 2;
        a.planeH[i] = (__half*)(ws + off); off += (size_t)256 * W * 32 * 2;
    }
    off = (off + 15) & ~(size_t)15;
    a.binP4 = (float4*)(ws + off);  off += (size_t)NBIN * CAP * 16;
    a.ovP4 = (float4*)(ws + off);   off += (size_t)OVCAP * 16;
    a.binIdx = (int*)(ws + off);    off += (size_t)NBIN * CAP * 4;
    a.ovIdx = (int*)(ws + off);     off += (size_t)OVCAP * 4;
    a.cnt = (int*)(ws + off);       off += (NBIN + 1) * 4;

    a.pts = (const float*)d_in[0];
    a.ts = (const float*)d_in[1];
    for (int i = 0; i < 6; ++i) {
        a.yl[i] = (const float*)d_in[2 + 3 * i];
        a.yha[i] = (const float*)d_in[3 + 3 * i];
        a.yhb[i] = (const float*)d_in[4 + 3 * i];
    }
    a.Npts = Npts;

    k1_l1_zero<<<768 + 17, 256, 0, stream>>>(a);
    k2_v2_scatter<<<7680 + 512, 256, 0, stream>>>(a);
    k3_ht<<<1536, 256, 0, stream>>>(a);

    SK s;
    for (int i = 0; i < 6; ++i) s.pl[i] = a.planeH[i];
    s.binP4 = a.binP4; s.binIdx = a.binIdx; s.cnt = a.cnt;
    s.ovP4 = a.ovP4; s.ovIdx = a.ovIdx;
    s.out = (float*)d_out;
    k4_sample<<<NBIN + 8, 256, 0, stream>>>(s);
}